// Round 13
// baseline (26.475 us; speedup 1.0000x reference)
//
#include <hip/hip_runtime.h>
#include <math.h>

#define SZ 256
#define KPTS 64
#define GROUPS 4
#define SEGS_PER (KPTS / GROUPS)   // 16 segments per thread
#define PX 4                       // pixels per thread
#define NBLK (4 * SZ)              // 1024 prod blocks: bn(4) x i(256)
#define K_SIGN 100000.0f
#define INV_2PI 0.15915494309189535f
#define PI_F 3.14159265358979323846f
#define HALFPI_F 1.57079632679489662f
// 2*K_SIGN*log2(e): tanh(K_SIGN*c) = 1 - 2/(exp2(K2_LOG2E*c)+1)
#define K2_LOG2E 288539.00817779269f
// angle clip equivalent of cos clip +-(1-1e-5)  (acos is monotone decreasing)
#define ANG_LO 4.4721373e-3f
#define ANG_HI 3.1371205e+0f
// atan minimax deg-9 on [0,1] (err ~1e-5 rad; validated in R9)
#define AT1 0.99997726f
#define AT3 -0.33262347f
#define AT5 0.19354346f
#define AT7 -0.11643287f
#define AT9 0.05265332f

__device__ __forceinline__ float fast_rcp(float x)  { return __builtin_amdgcn_rcpf(x); }
__device__ __forceinline__ float fast_sqrt(float x) { return __builtin_amdgcn_sqrtf(x); }
__device__ __forceinline__ float fast_exp2(float x) { return __builtin_amdgcn_exp2f(x); }

// d_ws: ws[blk] = per-block max, blk in [0,1024); fully rewritten every call.

// grid = 1024 blocks (bn x i), block = 256 threads.
// thread t: g = t&3 (16-seg group), slot = t>>2 in [0,64) -> FOUR pixels
// j = 4*slot + q, q=0..3 (same row i => shared mx, dxn, dx2, dd).
__global__ __launch_bounds__(256, 4) void contour_prod_kernel(
    const float* __restrict__ contour,   // [4][64][2]
    float* __restrict__ out,             // [4][256][256] unnormalized
    float* __restrict__ ws)              // [1024] per-block maxes
{
    __shared__ float2 cpt[KPTS + 1];
    __shared__ float wred[4];

    const int blk = blockIdx.x;
    const int i   = blk & 255;
    const int bn  = blk >> 8;

    const int t = threadIdx.x;
    if (t < KPTS) {
        float2 p = ((const float2*)contour)[bn * KPTS + t];
        cpt[t] = p;
        if (t == 0) cpt[KPTS] = p;      // wraparound dup
    }
    __syncthreads();

    const int g    = t & 3;
    const int slot = t >> 2;
    const int j0   = slot << 2;

    const float mxp = (float)i * (1.0f / (float)SZ);
    float my[PX];
    #pragma unroll
    for (int q = 0; q < PX; ++q)
        my[q] = (float)(j0 + q) * (1.0f / (float)SZ);

    const int base = g * SEGS_PER;

    float2 cp = cpt[base];
    float dxc = cp.x - mxp;
    const float dx2c = dxc * dxc;
    float dyc[PX], mn[PX], acc[PX];
    #pragma unroll
    for (int q = 0; q < PX; ++q) {
        dyc[q] = cp.y - my[q];
        mn[q]  = fmaf(dyc[q], dyc[q], dx2c);
        acc[q] = 0.0f;
    }

    #pragma unroll
    for (int kk = 0; kk < SEGS_PER; ++kk) {
        const float2 cn = cpt[base + kk + 1];
        const float dxn = cn.x - mxp;            // shared across 4 pixels
        const float dx2 = dxn * dxn;             // shared
        const float dd  = dxc * dxn;             // shared

        #pragma unroll
        for (int q = 0; q < PX; ++q) {
            const float dyn = cn.y - my[q];
            const float n2n = fmaf(dyn, dyn, dx2);
            mn[q] = fminf(mn[q], n2n);

            const float cross = fmaf(dyc[q], dxn, -dxc * dyn);
            const float dot   = fmaf(dyc[q], dyn, dd);

            const float yv = fabsf(cross);
            const float ad = fabsf(dot);
            const float mx_ = fmaxf(fmaxf(ad, yv), 1e-20f);
            const float mn_ = fminf(ad, yv);

            // tanh(K*cross) via exp2; its rcp is FUSED with the atan2 range
            // reduction: r = 1/(mx_*f) gives tan = mn_*(f*r), tanh = 1-2*mx_*r.
            const float kc = fminf(K2_LOG2E * cross, 100.0f);
            const float e  = fast_exp2(kc);
            const float f  = e + 1.0f;
            const float r  = fast_rcp(mx_ * f);

            const float tt = mn_ * (f * r);      // mn_/mx_ in [0,1]
            const float ss = tt * tt;
            float p = fmaf(ss, fmaf(ss, fmaf(ss, fmaf(ss, AT9, AT7), AT5),
                                    AT3), AT1);
            p *= tt;                              // atan(tt) in [0, pi/4]
            float ang = (yv > ad) ? (HALFPI_F - p) : p;
            ang = (dot < 0.0f) ? (PI_F - ang) : ang;
            ang = fminf(fmaxf(ang, ANG_LO), ANG_HI);   // reference cos-clip

            const float sgn = fmaf(-2.0f, mx_ * r, 1.0f);  // tanh(K*cross)

            acc[q] = fmaf(sgn, ang, acc[q]);
            dyc[q] = dyn;
        }
        dxc = dxn;
    }

    // combine 4 segment-groups per pixel (4-lane butterflies)
    #pragma unroll
    for (int q = 0; q < PX; ++q) {
        acc[q] += __shfl_xor(acc[q], 1, 64);
        acc[q] += __shfl_xor(acc[q], 2, 64);
        mn[q] = fminf(mn[q], __shfl_xor(mn[q], 1, 64));
        mn[q] = fminf(mn[q], __shfl_xor(mn[q], 2, 64));
    }

    float prod[PX];
    #pragma unroll
    for (int q = 0; q < PX; ++q)
        prod[q] = fabsf(acc[q]) * INV_2PI * fast_sqrt(mn[q]);

    if (g == 0) {
        ((float4*)out)[((bn << 8) + i) * (SZ / 4) + slot] =
            make_float4(prod[0], prod[1], prod[2], prod[3]);
    }

    // block max -> plain store
    float wmax = fmaxf(fmaxf(prod[0], prod[1]), fmaxf(prod[2], prod[3]));
    #pragma unroll
    for (int off = 32; off > 0; off >>= 1)
        wmax = fmaxf(wmax, __shfl_down(wmax, off, 64));
    if ((t & 63) == 0) wred[t >> 6] = wmax;
    __syncthreads();
    if (t == 0)
        ws[blk] = fmaxf(fmaxf(wred[0], wred[1]), fmaxf(wred[2], wred[3]));
}

// 256 blocks x 256 threads. Each block re-reduces ws[0..1023] (4 KB, L2-hit),
// then normalizes its 1024-pixel chunk (float4 per thread).
__global__ __launch_bounds__(256) void contour_norm_kernel(
    float4* __restrict__ out,
    const float* __restrict__ ws)
{
    __shared__ float wred[4];
    __shared__ float smax;

    const int t = threadIdx.x;
    const float4* w4 = (const float4*)ws;   // 256 float4

    float4 v0 = w4[t];
    float m = fmaxf(fmaxf(v0.x, v0.y), fmaxf(v0.z, v0.w));
    #pragma unroll
    for (int off = 32; off > 0; off >>= 1)
        m = fmaxf(m, __shfl_down(m, off, 64));
    if ((t & 63) == 0) wred[t >> 6] = m;
    __syncthreads();
    if (t == 0)
        smax = fmaxf(fmaxf(wred[0], wred[1]), fmaxf(wred[2], wred[3]));
    __syncthreads();

    const float inv = 1.0f / smax;           // one IEEE divide
    const int idx = blockIdx.x * 256 + t;
    float4 v = out[idx];
    v.x *= inv; v.y *= inv; v.z *= inv; v.w *= inv;
    out[idx] = v;
}

extern "C" void kernel_launch(void* const* d_in, const int* in_sizes, int n_in,
                              void* d_out, int out_size, void* d_ws, size_t ws_size,
                              hipStream_t stream)
{
    const float* contour = (const float*)d_in[0];   // [2][2][64][2] fp32
    float* out = (float*)d_out;                     // [2][2][256][256] fp32
    float* ws  = (float*)d_ws;

    contour_prod_kernel<<<NBLK, SZ, 0, stream>>>(contour, out, ws);
    contour_norm_kernel<<<out_size / 4 / 256, 256, 0, stream>>>((float4*)out, ws);
}

// Round 14
// 21.616 us; speedup vs baseline: 1.2248x; 1.2248x over previous
//
#include <hip/hip_runtime.h>
#include <math.h>

#define SZ 256
#define KPTS 64
#define GROUPS 4
#define SEGS_PER (KPTS / GROUPS)   // 16 segments per thread
#define PX 4                       // pixels per thread
#define NBLK (4 * SZ)              // 1024 prod blocks: bn(4) x i(256)
#define K_SIGN 100000.0f
#define EPS_C 1e-5f
#define INV_2PI 0.15915494309189535f
#define PI_F 3.14159265358979323846f
// 2*K_SIGN*log2(e): tanh(2K*c) = 1 - 2/(exp2(K2_LOG2E*c)+1)
#define K2_LOG2E 288539.00817779269f

__device__ __forceinline__ float fast_rcp(float x)  { return __builtin_amdgcn_rcpf(x); }
__device__ __forceinline__ float fast_sqrt(float x) { return __builtin_amdgcn_sqrtf(x); }
__device__ __forceinline__ float fast_rsq(float x)  { return __builtin_amdgcn_rsqf(x); }
__device__ __forceinline__ float fast_exp2(float x) { return __builtin_amdgcn_exp2f(x); }

// tanh(2K*cross) = 1 - 2/(exp2(K2_LOG2E*cross)+1); saturates cleanly.
__device__ __forceinline__ float fast_tanh_k(float cross) {
    float t = fast_exp2(K2_LOG2E * cross);
    return fmaf(-2.0f, fast_rcp(t + 1.0f), 1.0f);
}

// acos approx (Abramowitz-Stegun 4.4.45), max err ~6.7e-5 rad.
__device__ __forceinline__ float fast_acos(float x) {
    float ax = fabsf(x);
    float s  = fast_sqrt(1.0f - ax);
    float p  = s * fmaf(ax, fmaf(ax, fmaf(ax, -0.0187292994f, 0.0742610037f),
                                  -0.2121143937f), 1.5707288f);
    return (x >= 0.0f) ? p : (PI_F - p);
}

// d_ws: ws[blk*4 + wave] = per-wave max, [0,4096); fully rewritten every call.

// grid = 1024 blocks (bn x i), block = 256 threads.
// thread t: g = t&3 (16-seg group), slot = t>>2 in [0,64) -> FOUR pixels
// j = 4*slot + q, q=0..3 (same row i => shared mx, dxn, dx2, dd).
__global__ __launch_bounds__(256, 4) void contour_prod_kernel(
    const float* __restrict__ contour,   // [4][64][2]
    float* __restrict__ out,             // [4][256][256] unnormalized
    float* __restrict__ ws)              // [4096] per-wave maxes
{
    __shared__ float2 cpt[KPTS + 1];

    const int blk = blockIdx.x;
    const int i   = blk & 255;
    const int bn  = blk >> 8;

    const int t = threadIdx.x;
    if (t < KPTS) {
        float2 p = ((const float2*)contour)[bn * KPTS + t];
        cpt[t] = p;
        if (t == 0) cpt[KPTS] = p;      // wraparound dup
    }
    __syncthreads();

    const int g    = t & 3;
    const int slot = t >> 2;
    const int j0   = slot << 2;

    const float mx = (float)i * (1.0f / (float)SZ);
    float my[PX];
    #pragma unroll
    for (int q = 0; q < PX; ++q)
        my[q] = (float)(j0 + q) * (1.0f / (float)SZ);

    const int base = g * SEGS_PER;

    float2 cp = cpt[base];
    float dxc = cp.x - mx;
    const float dx2c = dxc * dxc;
    float dyc[PX], mn[PX], n2c[PX], acc[PX];
    #pragma unroll
    for (int q = 0; q < PX; ++q) {
        dyc[q] = cp.y - my[q];
        mn[q]  = fmaf(dyc[q], dyc[q], dx2c);
        n2c[q] = mn[q];
        acc[q] = 0.0f;
    }

    #pragma unroll
    for (int kk = 0; kk < SEGS_PER; ++kk) {
        const float2 cn = cpt[base + kk + 1];
        const float dxn = cn.x - mx;             // shared across 4 pixels
        const float dx2 = dxn * dxn;             // shared
        const float dd  = dxc * dxn;             // shared

        #pragma unroll
        for (int q = 0; q < PX; ++q) {
            const float dyn = cn.y - my[q];
            const float n2n = fmaf(dyn, dyn, dx2);
            mn[q] = fminf(mn[q], n2n);

            const float cross = fmaf(dyc[q], dxn, -dxc * dyn);
            const float dot   = fmaf(dyc[q], dyn, dd);

            float cosang = dot * fast_rsq(n2c[q] * n2n);
            cosang = fminf(fmaxf(cosang, -1.0f + EPS_C), 1.0f - EPS_C); // v_med3
            const float ang = fast_acos(cosang);
            const float sgn = fast_tanh_k(cross);

            acc[q] = fmaf(sgn, ang, acc[q]);

            dyc[q] = dyn;
            n2c[q] = n2n;
        }
        dxc = dxn;
    }

    // combine 4 segment-groups per pixel (4-lane butterflies)
    #pragma unroll
    for (int q = 0; q < PX; ++q) {
        acc[q] += __shfl_xor(acc[q], 1, 64);
        acc[q] += __shfl_xor(acc[q], 2, 64);
        mn[q] = fminf(mn[q], __shfl_xor(mn[q], 1, 64));
        mn[q] = fminf(mn[q], __shfl_xor(mn[q], 2, 64));
    }

    float prod[PX];
    #pragma unroll
    for (int q = 0; q < PX; ++q)
        prod[q] = fabsf(acc[q]) * INV_2PI * fast_sqrt(mn[q]);

    if (g == 0) {
        ((float4*)out)[((bn << 8) + i) * (SZ / 4) + slot] =
            make_float4(prod[0], prod[1], prod[2], prod[3]);
    }

    // per-wave max -> plain store (no LDS, no extra barrier)
    float wm = fmaxf(fmaxf(prod[0], prod[1]), fmaxf(prod[2], prod[3]));
    wm = fmaxf(wm, __shfl_xor(wm, 4, 64));
    wm = fmaxf(wm, __shfl_xor(wm, 8, 64));
    wm = fmaxf(wm, __shfl_xor(wm, 16, 64));
    wm = fmaxf(wm, __shfl_xor(wm, 32, 64));
    if ((t & 63) == 0)
        ws[(blk << 2) + (t >> 6)] = wm;
}

// 256 blocks x 256 threads. Each block re-reduces ws[0..4095] (16 KB, L2-hit),
// then normalizes its 1024-pixel chunk (float4 per thread).
__global__ __launch_bounds__(256) void contour_norm_kernel(
    float4* __restrict__ out,
    const float* __restrict__ ws)
{
    __shared__ float wred[4];
    __shared__ float smax;

    const int t = threadIdx.x;
    const float4* w4 = (const float4*)ws;   // 1024 float4

    float m = 0.0f;                          // prod >= 0
    #pragma unroll
    for (int r = 0; r < 4; ++r) {
        float4 v = w4[t + (r << 8)];
        m = fmaxf(m, fmaxf(fmaxf(v.x, v.y), fmaxf(v.z, v.w)));
    }
    #pragma unroll
    for (int off = 32; off > 0; off >>= 1)
        m = fmaxf(m, __shfl_down(m, off, 64));
    if ((t & 63) == 0) wred[t >> 6] = m;
    __syncthreads();
    if (t == 0)
        smax = fmaxf(fmaxf(wred[0], wred[1]), fmaxf(wred[2], wred[3]));
    __syncthreads();

    const float inv = 1.0f / smax;           // one IEEE divide
    const int idx = blockIdx.x * 256 + t;
    float4 v = out[idx];
    v.x *= inv; v.y *= inv; v.z *= inv; v.w *= inv;
    out[idx] = v;
}

extern "C" void kernel_launch(void* const* d_in, const int* in_sizes, int n_in,
                              void* d_out, int out_size, void* d_ws, size_t ws_size,
                              hipStream_t stream)
{
    const float* contour = (const float*)d_in[0];   // [2][2][64][2] fp32
    float* out = (float*)d_out;                     // [2][2][256][256] fp32
    float* ws  = (float*)d_ws;

    contour_prod_kernel<<<NBLK, SZ, 0, stream>>>(contour, out, ws);
    contour_norm_kernel<<<out_size / 4 / 256, 256, 0, stream>>>((float4*)out, ws);
}